// Round 1
// baseline (2082.391 us; speedup 1.0000x reference)
//
#include <hip/hip_runtime.h>

#define Bsz  256
#define Tlen 2048
#define Hdim 128
#define G3   384   // 3*H, gate order (r, z, n)

__device__ __forceinline__ float sigmoidf_(float v) { return 1.0f / (1.0f + __expf(-v)); }
__device__ __forceinline__ float tanhf_(float v)    { return 1.0f - 2.0f / (__expf(2.0f * v) + 1.0f); }

// grid = 256 blocks (one per batch element), block = 512 threads (8 waves).
// thread t: kc = t & 7   -> k-chunk [kc*16, kc*16+16)
//           rg = t >> 3  -> rows rg*6 .. rg*6+5 of Whh (64 groups * 6 = 384 rows)
// threads 0..127 ("gate threads", u = tid) own hidden unit u: combine gates,
// keep h_u in a register, and compute the Wfc imputation dot via shuffle.
__global__ __launch_bounds__(512)
void rnn_imp_kernel(const float* __restrict__ x,     // [B, T] (I=1)
                    const float* __restrict__ Wih,   // [384]  (I=1)
                    const float* __restrict__ Whh,   // [384, 128]
                    const float* __restrict__ bih,   // [384]
                    const float* __restrict__ bhh,   // [384]
                    const float* __restrict__ Wfc,   // [128]  (I=1)
                    const float* __restrict__ bfc,   // [1]
                    float* __restrict__ out_newin,   // [T, B]
                    float* __restrict__ out_pred)    // [B, T-1]
{
    __shared__ __align__(16) float x_s[Tlen];
    __shared__ __align__(16) float h_s[Hdim];
    __shared__ __align__(16) float gh_s[G3];
    __shared__ float xp_s[2];

    const int tid = threadIdx.x;
    const int b   = blockIdx.x;
    const int kc  = tid & 7;
    const int rg  = tid >> 3;

    // stage this batch row's x into LDS (contiguous 8 KB, coalesced)
    for (int i = tid; i < Tlen; i += 512) x_s[i] = x[b * Tlen + i];

    // load this thread's Whh strip into registers: 6 rows x 16 k = 96 floats
    float w[6][16];
#pragma unroll
    for (int i = 0; i < 6; ++i) {
        const float4* wp = (const float4*)(Whh + (rg * 6 + i) * Hdim + kc * 16);
#pragma unroll
        for (int j = 0; j < 4; ++j) {
            float4 v = wp[j];
            w[i][4 * j + 0] = v.x; w[i][4 * j + 1] = v.y;
            w[i][4 * j + 2] = v.z; w[i][4 * j + 3] = v.w;
        }
    }

    // gate-thread constants
    float wih_r = 0.f, wih_z = 0.f, wih_n = 0.f;
    float bih_r = 0.f, bih_z = 0.f, bih_n = 0.f;
    float bhh_r = 0.f, bhh_z = 0.f, bhh_n = 0.f;
    float wfc_u = 0.f;
    const int u = tid;
    if (u < Hdim) {
        wih_r = Wih[u]; wih_z = Wih[u + 128]; wih_n = Wih[u + 256];
        bih_r = bih[u]; bih_z = bih[u + 128]; bih_n = bih[u + 256];
        bhh_r = bhh[u]; bhh_z = bhh[u + 128]; bhh_n = bhh[u + 256];
        wfc_u = Wfc[u];
    }
    const float bfc0 = bfc[0];
    float h_old = 0.0f;

    __syncthreads();

    // ---- step 0: no imputation, h_prev = 0 (so Whh@h = 0, gh = bhh) ----
    if (u < Hdim) {
        float cur = x_s[0];
        float pr  = wih_r * cur + bih_r + bhh_r;
        float pz  = wih_z * cur + bih_z + bhh_z;
        float r   = sigmoidf_(pr);
        float z   = sigmoidf_(pz);
        float n   = tanhf_(wih_n * cur + bih_n + r * bhh_n);
        float hn  = (1.0f - z) * n;       // + z*0
        h_old = hn;
        h_s[u] = hn;
        if (u == 0) out_newin[0 * Bsz + b] = cur;   // raw x[0], sentinels kept
    }
    __syncthreads();

    // ---- steps 1 .. T-1 ----
#pragma unroll 1
    for (int t = 1; t < Tlen; ++t) {
        // phase A: partial dot gh[row] over this thread's k-chunk
        float hv[16];
        {
            const float4* hp = (const float4*)(h_s + kc * 16);
#pragma unroll
            for (int j = 0; j < 4; ++j) {
                float4 v = hp[j];
                hv[4 * j + 0] = v.x; hv[4 * j + 1] = v.y;
                hv[4 * j + 2] = v.z; hv[4 * j + 3] = v.w;
            }
        }
        float acc[6];
#pragma unroll
        for (int i = 0; i < 6; ++i) {
            float a0 = 0.f, a1 = 0.f;
#pragma unroll
            for (int k = 0; k < 16; k += 2) {
                a0 += w[i][k] * hv[k];
                a1 += w[i][k + 1] * hv[k + 1];
            }
            acc[i] = a0 + a1;
        }
        // phase B: reduce over the 8 k-chunks (lanes kc=0..7 adjacent)
#pragma unroll
        for (int d = 1; d < 8; d <<= 1) {
#pragma unroll
            for (int i = 0; i < 6; ++i) acc[i] += __shfl_xor(acc[i], d);
        }
        if (kc == 0) {
#pragma unroll
            for (int i = 0; i < 6; ++i) gh_s[rg * 6 + i] = acc[i];
        }
        // imputation dot x_hat = Wfc . h_{t-1} + bfc (gate threads, h in reg)
        if (u < Hdim) {
            float p = wfc_u * h_old;
#pragma unroll
            for (int d = 1; d < 64; d <<= 1) p += __shfl_xor(p, d);
            if ((tid & 63) == 0) xp_s[tid >> 6] = p;
        }
        __syncthreads();

        // phase C: gate combine on threads 0..127
        if (u < Hdim) {
            float xh  = xp_s[0] + xp_s[1] + bfc0;
            float xt  = x_s[t];
            float cur = (xt == 128.0f) ? xh : xt;
            float ghr = gh_s[u] + bhh_r;
            float ghz = gh_s[u + 128] + bhh_z;
            float ghn = gh_s[u + 256] + bhh_n;
            float r   = sigmoidf_(wih_r * cur + bih_r + ghr);
            float z   = sigmoidf_(wih_z * cur + bih_z + ghz);
            float n   = tanhf_(wih_n * cur + bih_n + r * ghn);
            float hn  = (1.0f - z) * n + z * h_old;
            h_old = hn;
            h_s[u] = hn;
            if (u == 0) {
                out_newin[t * Bsz + b]            = cur;
                out_pred[b * (Tlen - 1) + (t - 1)] = xh;
            }
        }
        __syncthreads();
    }
}

extern "C" void kernel_launch(void* const* d_in, const int* in_sizes, int n_in,
                              void* d_out, int out_size, void* d_ws, size_t ws_size,
                              hipStream_t stream) {
    const float* x   = (const float*)d_in[0];
    const float* Wih = (const float*)d_in[1];
    const float* Whh = (const float*)d_in[2];
    const float* bih = (const float*)d_in[3];
    const float* bhh = (const float*)d_in[4];
    const float* Wfc = (const float*)d_in[5];
    const float* bfc = (const float*)d_in[6];

    float* out_newin = (float*)d_out;                 // [T*B] = 524288
    float* out_pred  = out_newin + Tlen * Bsz;        // [B*(T-1)] = 524032

    rnn_imp_kernel<<<Bsz, 512, 0, stream>>>(x, Wih, Whh, bih, bhh, Wfc, bfc,
                                            out_newin, out_pred);
}

// Round 3
// 1913.708 us; speedup vs baseline: 1.0881x; 1.0881x over previous
//
#include <hip/hip_runtime.h>

#define Bsz  256
#define Tlen 2048
#define Hdim 128
#define HP   160   // padded h buffer: unit u stored at u + (u>>4)*4 (max 155)

typedef float vf2 __attribute__((ext_vector_type(2)));

__device__ __forceinline__ float sigmoidf_(float v) { return 1.0f / (1.0f + __expf(-v)); }
__device__ __forceinline__ float tanhf_(float v)    { return 1.0f - 2.0f / (__expf(2.0f * v) + 1.0f); }

// DPP butterfly add over groups of 8 consecutive lanes (VALU pipe, no LDS).
// ctrl must be a compile-time constant for the builtin.
template <int CTRL>
__device__ __forceinline__ float dpp_add(float v) {
    int t = __builtin_amdgcn_update_dpp(0, __float_as_int(v), CTRL, 0xf, 0xf, true);
    return v + __int_as_float(t);
}
// 0xB1 = quad_perm xor1, 0x4E = quad_perm xor2, 0x141 = row_half_mirror
// (mirror within row of 16; after levels 1+2 each quad is uniform, so the
// mirror delivers the other quad's total -> full 8-lane sum in lanes 0..7
// of each 8-group... mirror pairs lane l with 15-l within the 16-lane row:
// for l in 0..7 partner is 15-l in 8..15 (other 8-group of the same row).
// That's WRONG for two independent 8-groups per row -- so instead use
// row_shl/row_shr? Keep it simple: do the 3rd level with ds_swizzle-free
// DPP row_ror:8? Not xor. Use instead quad_perm for levels 1,2 and a
// single ds_swizzle xor-4 for level 3 (1 DS op per 7 reductions is cheap).
__device__ __forceinline__ float red8(float v) {
    v = dpp_add<0xB1>(v);   // xor 1 within quad
    v = dpp_add<0x4E>(v);   // xor 2 within quad
    // level 3: xor 4 across quads — BitMode swizzle xor_mask=4, and=0x1F
    int t = __builtin_amdgcn_ds_swizzle(__float_as_int(v), 0x101F);
    return v + __int_as_float(t);
}

// grid = 256 blocks (one batch row per block), block = 512 threads (8 waves).
// thread t: kc = t & 7  -> k-chunk [kc*16, kc*16+16)
//           rg = t >> 3 -> unit pair u0 = 2*rg, u0+1; owns Whh rows
//           {u0, u0+1} + {0,128,256} (r,z,n gates together) over its k-chunk.
// After the 8-lane reduce, EVERY lane of a group holds the full dot, so
// gate math runs unpredicated; only the LDS h-write is predicated on kc==0.
__global__ __launch_bounds__(512, 2)
void rnn_imp_kernel(const float* __restrict__ x,     // [B, T] (I=1)
                    const float* __restrict__ Wih,   // [384]
                    const float* __restrict__ Whh,   // [384, 128]
                    const float* __restrict__ bih,   // [384]
                    const float* __restrict__ bhh,   // [384]
                    const float* __restrict__ Wfc,   // [128]
                    const float* __restrict__ bfc,   // [1]
                    float* __restrict__ out_newin,   // [T, B]
                    float* __restrict__ out_pred)    // [B, T-1]
{
    __shared__ __align__(16) float x_s[Tlen + 4];
    __shared__ __align__(16) float h_s[2][HP];

    const int tid = threadIdx.x;
    const int b   = blockIdx.x;
    const int kc  = tid & 7;
    const int rg  = tid >> 3;
    const int u0  = rg * 2;

    // stage x row (coalesced) and zero h buffer 0
    for (int i = tid; i < Tlen; i += 512) x_s[i] = x[b * Tlen + i];
    if (tid < HP) h_s[0][tid] = 0.0f;

    // Whh strip: gates-together rows, 6 rows x 16 k = 96 floats
    vf2 w2[3][2][8];
#pragma unroll
    for (int g = 0; g < 3; ++g)
#pragma unroll
        for (int un = 0; un < 2; ++un) {
            const float4* wp = (const float4*)(Whh + (g * Hdim + u0 + un) * Hdim + kc * 16);
#pragma unroll
            for (int j = 0; j < 4; ++j) {
                float4 v = wp[j];
                w2[g][un][2 * j + 0] = vf2{v.x, v.y};
                w2[g][un][2 * j + 1] = vf2{v.z, v.w};
            }
        }
    // Wfc chunk for the in-register imputation dot
    vf2 wfc2[8];
    {
        const float4* fp = (const float4*)(Wfc + kc * 16);
#pragma unroll
        for (int j = 0; j < 4; ++j) {
            float4 v = fp[j];
            wfc2[2 * j + 0] = vf2{v.x, v.y};
            wfc2[2 * j + 1] = vf2{v.z, v.w};
        }
    }
    // per-unit gate constants (loaded by all lanes of the group; identical)
    float wih_g[3][2], bih_g[3][2], bhh_g[3][2];
#pragma unroll
    for (int g = 0; g < 3; ++g)
#pragma unroll
        for (int un = 0; un < 2; ++un) {
            wih_g[g][un] = Wih[g * Hdim + u0 + un];
            bih_g[g][un] = bih[g * Hdim + u0 + un];
            bhh_g[g][un] = bhh[g * Hdim + u0 + un];
        }
    const float bfc0 = bfc[0];
    float h_old0 = 0.0f, h_old1 = 0.0f;

    const int rbase = kc * 20;                      // padded chunk base (words)
    const int pu0   = u0 + (u0 >> 4) * 4;           // padded write position

    __syncthreads();

#pragma unroll 1
    for (int t = 0; t < Tlen; ++t) {
        const float* hb = h_s[t & 1];
        float*       hw = h_s[(t + 1) & 1];
        float xt = x_s[t];

        // h chunk: 4x ds_read_b128, bases kc*20 words -> 8 distinct banks
        const float4* hp = (const float4*)(hb + rbase);
        float4 q0 = hp[0], q1 = hp[1], q2 = hp[2], q3 = hp[3];
        vf2 hv[8] = { vf2{q0.x, q0.y}, vf2{q0.z, q0.w},
                      vf2{q1.x, q1.y}, vf2{q1.z, q1.w},
                      vf2{q2.x, q2.y}, vf2{q2.z, q2.w},
                      vf2{q3.x, q3.y}, vf2{q3.z, q3.w} };

        vf2 a2[3][2] = {{vf2{0.f,0.f}, vf2{0.f,0.f}},
                        {vf2{0.f,0.f}, vf2{0.f,0.f}},
                        {vf2{0.f,0.f}, vf2{0.f,0.f}}};
        vf2 xp2 = vf2{0.f, 0.f};
#pragma unroll
        for (int i = 0; i < 8; ++i) {
            vf2 h2 = hv[i];
            a2[0][0] += w2[0][0][i] * h2;
            a2[0][1] += w2[0][1][i] * h2;
            a2[1][0] += w2[1][0][i] * h2;
            a2[1][1] += w2[1][1][i] * h2;
            a2[2][0] += w2[2][0][i] * h2;
            a2[2][1] += w2[2][1][i] * h2;
            xp2      += wfc2[i] * h2;
        }
        // 8-lane butterfly; every lane ends with the full sums
        float ar0 = red8(a2[0][0].x + a2[0][0].y);
        float ar1 = red8(a2[0][1].x + a2[0][1].y);
        float az0 = red8(a2[1][0].x + a2[1][0].y);
        float az1 = red8(a2[1][1].x + a2[1][1].y);
        float an0 = red8(a2[2][0].x + a2[2][0].y);
        float an1 = red8(a2[2][1].x + a2[2][1].y);
        float xp  = red8(xp2.x + xp2.y);

        float xh  = xp + bfc0;
        float cur = ((xt == 128.0f) && (t != 0)) ? xh : xt;

        float r0 = sigmoidf_(wih_g[0][0] * cur + bih_g[0][0] + ar0 + bhh_g[0][0]);
        float z0 = sigmoidf_(wih_g[1][0] * cur + bih_g[1][0] + az0 + bhh_g[1][0]);
        float n0 = tanhf_(wih_g[2][0] * cur + bih_g[2][0] + r0 * (an0 + bhh_g[2][0]));
        float hn0 = (1.0f - z0) * n0 + z0 * h_old0;

        float r1 = sigmoidf_(wih_g[0][1] * cur + bih_g[0][1] + ar1 + bhh_g[0][1]);
        float z1 = sigmoidf_(wih_g[1][1] * cur + bih_g[1][1] + az1 + bhh_g[1][1]);
        float n1 = tanhf_(wih_g[2][1] * cur + bih_g[2][1] + r1 * (an1 + bhh_g[2][1]));
        float hn1 = (1.0f - z1) * n1 + z1 * h_old1;

        h_old0 = hn0; h_old1 = hn1;

        if (kc == 0) {
            *(float2*)(hw + pu0) = make_float2(hn0, hn1);
        }
        if (tid == 0) {
            out_newin[t * Bsz + b] = cur;
            if (t != 0) out_pred[b * (Tlen - 1) + (t - 1)] = xh;
        }
        __syncthreads();
    }
}

extern "C" void kernel_launch(void* const* d_in, const int* in_sizes, int n_in,
                              void* d_out, int out_size, void* d_ws, size_t ws_size,
                              hipStream_t stream) {
    const float* x   = (const float*)d_in[0];
    const float* Wih = (const float*)d_in[1];
    const float* Whh = (const float*)d_in[2];
    const float* bih = (const float*)d_in[3];
    const float* bhh = (const float*)d_in[4];
    const float* Wfc = (const float*)d_in[5];
    const float* bfc = (const float*)d_in[6];

    float* out_newin = (float*)d_out;                 // [T*B] = 524288
    float* out_pred  = out_newin + Tlen * Bsz;        // [B*(T-1)] = 524032

    rnn_imp_kernel<<<Bsz, 512, 0, stream>>>(x, Wih, Whh, bih, bhh, Wfc, bfc,
                                            out_newin, out_pred);
}

// Round 4
// 1852.980 us; speedup vs baseline: 1.1238x; 1.0328x over previous
//
#include <hip/hip_runtime.h>

#define Bsz  256
#define Tlen 2048
#define Hdim 128
#define HP   160   // padded h buffer: unit u stored at u + (u>>4)*4 (max 155)

typedef float vf2 __attribute__((ext_vector_type(2)));

__device__ __forceinline__ float sigmoidf_(float v) { return 1.0f / (1.0f + __expf(-v)); }
__device__ __forceinline__ float tanhf_(float v)    { return 1.0f - 2.0f / (__expf(2.0f * v) + 1.0f); }

// Keep a value pinned in a VGPR: opaque to remat, so the allocator cannot
// re-load it from memory inside the t-loop.
__device__ __forceinline__ void pin2(vf2& v) { asm volatile("" : "+v"(v)); }

// DPP butterfly add over groups of 8 consecutive lanes — pure VALU pipe.
template <int CTRL>
__device__ __forceinline__ float dpp_add(float v) {
    int t = __builtin_amdgcn_update_dpp(0, __float_as_int(v), CTRL, 0xf, 0xf, true);
    return v + __int_as_float(t);
}
// 0xB1 = quad_perm xor1, 0x4E = quad_perm xor2,
// 0x141 = row_half_mirror: lane l <-> (l&~7)|(7-(l&7)) — after levels 1+2 each
// quad is uniform, so the half-mirror delivers the other quad's sum within the
// SAME 8-lane group. Full 8-lane allreduce, zero DS ops.
__device__ __forceinline__ float red8(float v) {
    v = dpp_add<0xB1>(v);
    v = dpp_add<0x4E>(v);
    v = dpp_add<0x141>(v);
    return v;
}

// grid = 256 blocks (one batch row per block), block = 512 threads (8 waves).
// thread t: kc = t & 7  -> k-chunk [kc*16, kc*16+16)
//           rg = t >> 3 -> unit pair u0 = 2*rg, u0+1; owns Whh rows
//           {u0, u0+1} x {r,z,n} over its k-chunk (96 weights, register-resident).
// After the 8-lane DPP allreduce every lane holds the full dots -> gate math
// runs unpredicated; only the LDS h-write is predicated on kc==0.
__global__ __launch_bounds__(512)
__attribute__((amdgpu_waves_per_eu(2, 2)))
void rnn_imp_kernel(const float* __restrict__ x,     // [B, T] (I=1)
                    const float* __restrict__ Wih,   // [384]
                    const float* __restrict__ Whh,   // [384, 128]
                    const float* __restrict__ bih,   // [384]
                    const float* __restrict__ bhh,   // [384]
                    const float* __restrict__ Wfc,   // [128]
                    const float* __restrict__ bfc,   // [1]
                    float* __restrict__ out_newin,   // [T, B]
                    float* __restrict__ out_pred)    // [B, T-1]
{
    __shared__ __align__(16) float x_s[Tlen + 4];
    __shared__ __align__(16) float h_s[2][HP];

    const int tid = threadIdx.x;
    const int b   = blockIdx.x;
    const int kc  = tid & 7;
    const int rg  = tid >> 3;
    const int u0  = rg * 2;

    // stage x row (coalesced) and zero h buffer 0
    for (int i = tid; i < Tlen; i += 512) x_s[i] = x[b * Tlen + i];
    if (tid < HP) h_s[0][tid] = 0.0f;

    // Whh strip: gates-together rows, 6 rows x 16 k = 96 floats
    vf2 w2[3][2][8];
#pragma unroll
    for (int g = 0; g < 3; ++g)
#pragma unroll
        for (int un = 0; un < 2; ++un) {
            const float4* wp = (const float4*)(Whh + (g * Hdim + u0 + un) * Hdim + kc * 16);
#pragma unroll
            for (int j = 0; j < 4; ++j) {
                float4 v = wp[j];
                w2[g][un][2 * j + 0] = vf2{v.x, v.y};
                w2[g][un][2 * j + 1] = vf2{v.z, v.w};
            }
        }
    // Wfc chunk for the in-register imputation dot
    vf2 wfc2[8];
    {
        const float4* fp = (const float4*)(Wfc + kc * 16);
#pragma unroll
        for (int j = 0; j < 4; ++j) {
            float4 v = fp[j];
            wfc2[2 * j + 0] = vf2{v.x, v.y};
            wfc2[2 * j + 1] = vf2{v.z, v.w};
        }
    }
    // Pin all weights into VGPRs (non-rematerializable from here on).
#pragma unroll
    for (int g = 0; g < 3; ++g)
#pragma unroll
        for (int un = 0; un < 2; ++un)
#pragma unroll
            for (int i = 0; i < 8; ++i) pin2(w2[g][un][i]);
#pragma unroll
    for (int i = 0; i < 8; ++i) pin2(wfc2[i]);

    // per-unit gate constants (identical across the 8 lanes of a group)
    float wih_g[3][2], bih_g[3][2], bhh_g[3][2];
#pragma unroll
    for (int g = 0; g < 3; ++g)
#pragma unroll
        for (int un = 0; un < 2; ++un) {
            wih_g[g][un] = Wih[g * Hdim + u0 + un];
            bih_g[g][un] = bih[g * Hdim + u0 + un];
            bhh_g[g][un] = bhh[g * Hdim + u0 + un];
        }
    const float bfc0 = bfc[0];
    float h_old0 = 0.0f, h_old1 = 0.0f;

    const int rbase = kc * 20;                      // padded chunk base (words)
    const int pu0   = u0 + (u0 >> 4) * 4;           // padded write position

    __syncthreads();

#pragma unroll 1
    for (int t = 0; t < Tlen; ++t) {
        const float* hb = h_s[t & 1];
        float*       hw = h_s[(t + 1) & 1];
        float xt = x_s[t];

        // h chunk: 4x ds_read_b128, bases kc*20 words -> 8 distinct banks
        const float4* hp = (const float4*)(hb + rbase);
        float4 q0 = hp[0], q1 = hp[1], q2 = hp[2], q3 = hp[3];
        vf2 hv[8] = { vf2{q0.x, q0.y}, vf2{q0.z, q0.w},
                      vf2{q1.x, q1.y}, vf2{q1.z, q1.w},
                      vf2{q2.x, q2.y}, vf2{q2.z, q2.w},
                      vf2{q3.x, q3.y}, vf2{q3.z, q3.w} };

        vf2 a2[3][2] = {{vf2{0.f,0.f}, vf2{0.f,0.f}},
                        {vf2{0.f,0.f}, vf2{0.f,0.f}},
                        {vf2{0.f,0.f}, vf2{0.f,0.f}}};
        vf2 xp2 = vf2{0.f, 0.f};
#pragma unroll
        for (int i = 0; i < 8; ++i) {
            vf2 h2 = hv[i];
            a2[0][0] += w2[0][0][i] * h2;
            a2[0][1] += w2[0][1][i] * h2;
            a2[1][0] += w2[1][0][i] * h2;
            a2[1][1] += w2[1][1][i] * h2;
            a2[2][0] += w2[2][0][i] * h2;
            a2[2][1] += w2[2][1][i] * h2;
            xp2      += wfc2[i] * h2;
        }
        // 8-lane DPP butterfly; every lane ends with the full sums
        float ar0 = red8(a2[0][0].x + a2[0][0].y);
        float ar1 = red8(a2[0][1].x + a2[0][1].y);
        float az0 = red8(a2[1][0].x + a2[1][0].y);
        float az1 = red8(a2[1][1].x + a2[1][1].y);
        float an0 = red8(a2[2][0].x + a2[2][0].y);
        float an1 = red8(a2[2][1].x + a2[2][1].y);
        float xp  = red8(xp2.x + xp2.y);

        float xh  = xp + bfc0;
        float cur = ((xt == 128.0f) && (t != 0)) ? xh : xt;

        float r0 = sigmoidf_(wih_g[0][0] * cur + bih_g[0][0] + ar0 + bhh_g[0][0]);
        float z0 = sigmoidf_(wih_g[1][0] * cur + bih_g[1][0] + az0 + bhh_g[1][0]);
        float n0 = tanhf_(wih_g[2][0] * cur + bih_g[2][0] + r0 * (an0 + bhh_g[2][0]));
        float hn0 = (1.0f - z0) * n0 + z0 * h_old0;

        float r1 = sigmoidf_(wih_g[0][1] * cur + bih_g[0][1] + ar1 + bhh_g[0][1]);
        float z1 = sigmoidf_(wih_g[1][1] * cur + bih_g[1][1] + az1 + bhh_g[1][1]);
        float n1 = tanhf_(wih_g[2][1] * cur + bih_g[2][1] + r1 * (an1 + bhh_g[2][1]));
        float hn1 = (1.0f - z1) * n1 + z1 * h_old1;

        h_old0 = hn0; h_old1 = hn1;

        if (kc == 0) {
            *(float2*)(hw + pu0) = make_float2(hn0, hn1);
        }
        if (tid == 0) {
            out_newin[t * Bsz + b] = cur;
            if (t != 0) out_pred[b * (Tlen - 1) + (t - 1)] = xh;
        }
        __syncthreads();
    }
}

extern "C" void kernel_launch(void* const* d_in, const int* in_sizes, int n_in,
                              void* d_out, int out_size, void* d_ws, size_t ws_size,
                              hipStream_t stream) {
    const float* x   = (const float*)d_in[0];
    const float* Wih = (const float*)d_in[1];
    const float* Whh = (const float*)d_in[2];
    const float* bih = (const float*)d_in[3];
    const float* bhh = (const float*)d_in[4];
    const float* Wfc = (const float*)d_in[5];
    const float* bfc = (const float*)d_in[6];

    float* out_newin = (float*)d_out;                 // [T*B] = 524288
    float* out_pred  = out_newin + Tlen * Bsz;        // [B*(T-1)] = 524032

    rnn_imp_kernel<<<Bsz, 512, 0, stream>>>(x, Wih, Whh, bih, bhh, Wfc, bfc,
                                            out_newin, out_pred);
}